// Round 19
// baseline (503.481 us; speedup 1.0000x reference)
//
#include <hip/hip_runtime.h>

// QANet attention layer on MI355X (gfx950).
// B=40,S=128,H=768, NP=100, PL=20, HID=100, N=4000 sequences.
// Round 19: occupancy experiment on the pre-GEMM: BK 64->32 halves LDS to
// 36 KB -> 4 blocks/CU (16 waves/CU vs 8). 24 iters, counted-vmcnt dbuf,
// swizzle slot ^= (row ^ row>>2)&3 (2-way max, free). B staged as 10 16-row
// segs (waves 0-1 take 3, waves 2-3 take 2; per-wave vmcnt 5/4).
// Everything else identical to r18 (481.3 us verified).

typedef unsigned short ushort_t;
typedef unsigned int u32;
typedef __attribute__((ext_vector_type(8))) short short8;
typedef __attribute__((ext_vector_type(4))) float f32x4;
typedef __attribute__((address_space(1))) const u32 gu32;
typedef __attribute__((address_space(3))) u32 lu32;

__device__ __forceinline__ ushort_t f2bf(float f) {
  u32 x = __builtin_bit_cast(u32, f);
  u32 r = (x + 0x7fffu + ((x >> 16) & 1u)) >> 16;
  return (ushort_t)r;
}
__device__ __forceinline__ float bflo(u32 u) { return __builtin_bit_cast(float, u << 16); }
__device__ __forceinline__ float bfhi(u32 u) { return __builtin_bit_cast(float, u & 0xffff0000u); }
__device__ __forceinline__ u32 cvtpk(float lo, float hi) {
  u32 r;
  asm("v_cvt_pk_bf16_f32 %0, %1, %2" : "=v"(r) : "v"(lo), "v"(hi));
  return r;
}

__device__ __forceinline__ float sigm(float x) { return 1.f / (1.f + __expf(-x)); }
__device__ __forceinline__ float tanh_f(float x) { return 1.f - 2.f / (__expf(2.f * x) + 1.f); }

// ---------------- fused prep: weights | bert-derived | convert | part1 ----------------

__global__ __launch_bounds__(256) void prep_all(
    const float* __restrict__ Wih_f, const float* __restrict__ Wih_b,
    const float* __restrict__ Whh_f, const float* __restrict__ Whh_b,
    const float* __restrict__ bih_f, const float* __restrict__ bhh_f,
    const float* __restrict__ bih_b, const float* __restrict__ bhh_b,
    const float* __restrict__ projW, const float* __restrict__ attpW,
    ushort_t* __restrict__ wihcat, ushort_t* __restrict__ whhcat,
    float* __restrict__ biascat, ushort_t* __restrict__ projw_bf,
    ushort_t* __restrict__ attpw_bf,
    const float* __restrict__ bert, const float* __restrict__ W3,
    ushort_t* __restrict__ bw3, ushort_t* __restrict__ bT, ushort_t* __restrict__ cat,
    const float4* __restrict__ x4, ushort_t* __restrict__ xb,
    const float* __restrict__ W1w, const float* __restrict__ W1b,
    float* __restrict__ part1)
{
  __shared__ ushort_t tl[64 * 130];
  int bid = blockIdx.x, tid = threadIdx.x;
  if (bid < 512) {
    const int TOT = 614400 + 102400 + 800 + 196608 + 2359296;
    for (int idx = bid * 256 + tid; idx < TOT; idx += 512 * 256) {
      if (idx < 614400) {                       // Wih cat [800][768]
        int g = idx / 768, k = idx % 768;
        float v = g < 400 ? Wih_f[g * 768 + k] : Wih_b[(g - 400) * 768 + k];
        wihcat[idx] = f2bf(v);
      } else if (idx < 716800) {                // Whh cat padded [2][400][128]
        int e = idx - 614400; int g = e / 128, j = e % 128;
        float v = 0.f;
        if (j < 100) v = g < 400 ? Whh_f[g * 100 + j] : Whh_b[(g - 400) * 100 + j];
        whhcat[e] = f2bf(v);
      } else if (idx < 717600) {                // bias cat [800]
        int g = idx - 716800;
        biascat[g] = g < 400 ? bih_f[g] + bhh_f[g] : bih_b[g - 400] + bhh_b[g - 400];
      } else if (idx < 914208) {                // projW padded [768][256]
        int e = idx - 717600; int o = e / 256, j = e % 256;
        float v = 0.f;
        if (j < 100) v = projW[o * 200 + j];
        else if (j >= 128 && j < 228) v = projW[o * 200 + 100 + (j - 128)];
        projw_bf[e] = f2bf(v);
      } else {                                  // attpW [768][3072]
        int e = idx - 914208;
        attpw_bf[e] = f2bf(attpW[e]);
      }
    }
  } else if (bid < 992) {
    int e0 = bid - 512;
    int ht = e0 % 12, b = e0 / 12;
    int h0 = ht * 64;
    for (int e = tid; e < 8192; e += 256) {
      int t = e >> 6, hh = e & 63;
      float v = bert[((size_t)b * 128 + t) * 768 + h0 + hh];
      ushort_t vb = f2bf(v);
      bw3[((size_t)b * 128 + t) * 768 + h0 + hh] = f2bf(v * W3[h0 + hh]);
      cat[((size_t)b * 128 + t) * 3072 + h0 + hh] = vb;
      tl[hh * 130 + t] = vb;
    }
    __syncthreads();
    for (int e = tid; e < 8192; e += 256) {
      int hh = e >> 7, t = e & 127;
      bT[((size_t)b * 768 + h0 + hh) * 128 + t] = tl[hh * 130 + t];
    }
  } else if (bid < 3040) {
    for (int i = (bid - 992) * 256 + tid; i < 15360000; i += 2048 * 256) {
      int seq = i / 3840;
      int rem = i - seq * 3840;
      int t = rem / 192;
      int k4 = rem - t * 192;
      float4 v = x4[i];
      ushort4 o;
      o.x = f2bf(v.x); o.y = f2bf(v.y); o.z = f2bf(v.z); o.w = f2bf(v.w);
      *reinterpret_cast<ushort4*>(&xb[((size_t)t * 4000 + seq) * 768 + k4 * 4]) = o;
    }
  } else {
    int row = (bid - 3040) * 4 + (tid >> 6);
    int lane = tid & 63;
    const float* x = bert + (size_t)row * 768;
    float s = 0.f;
    for (int k = lane; k < 768; k += 64) s += x[k] * W1w[k];
    for (int off = 32; off; off >>= 1) s += __shfl_down(s, off);
    if (lane == 0) part1[row] = s + W1b[0];
  }
}

// ---------------- pre GEMM: 128x160 tiles, BK=32, counted-vmcnt dbuf ----------------
// LDS 36 KB -> 4 blocks/CU. Swizzle: slot ^= (row ^ row>>2)&3 (<=2-way).
// A: 8 segs of 16 rows (2/wave). B: 10 segs (waves 0-1: 3, waves 2-3: 2).

__global__ __launch_bounds__(256) void gemm_pre32(
    const ushort_t* __restrict__ A,     // x_bf [20][4000][768]
    const ushort_t* __restrict__ B,     // wihcat [800][768]
    const float* __restrict__ bias,
    ushort_t* __restrict__ P)
{
  __shared__ __align__(16) ushort_t lsA[2][128 * 32];   // 16 KB
  __shared__ __align__(16) ushort_t lsB[2][160 * 32];   // 20 KB
  int bid = blockIdx.x;
  int xcd = bid & 7, slot0 = bid >> 3;
  int L = (xcd < 5) ? xcd * 391 + slot0 : 1955 + (xcd - 5) * 390 + slot0;
  int bm = L / 5, bn = L - bm * 5;
  int m0 = bm * 128, n0 = bn * 160;
  int tid = threadIdx.x, lane = tid & 63, w = tid >> 6;
  int wr = w >> 1, wc = w & 1;
  int l15 = lane & 15, lk = lane >> 4;
  f32x4 acc[4][5];
  #pragma unroll
  for (int i = 0; i < 4; ++i)
    #pragma unroll
    for (int j = 0; j < 5; ++j)
      #pragma unroll
      for (int r = 0; r < 4; ++r) acc[i][j][r] = 0.f;

  // staging lane coords: seg covers 16 rows x 4 slots of 16B; lane=(row-rs)*4+physlot
  int srow = lane >> 2, sphys = lane & 3;
  auto stage = [&](int kt, int bf) {
    #pragma unroll
    for (int i = 0; i < 2; ++i) {            // A segs
      int seg = w * 2 + i;
      int row = seg * 16 + srow;
      int sl = sphys ^ ((row ^ (row >> 2)) & 3);
      __builtin_amdgcn_global_load_lds(
          (gu32*)(A + (size_t)(m0 + row) * 768 + kt * 32 + sl * 8),
          (lu32*)(&lsA[bf][seg * 512]), 16, 0, 0);
    }
    #pragma unroll
    for (int i = 0; i < 2; ++i) {            // B segs 0..7
      int seg = w * 2 + i;
      int row = seg * 16 + srow;
      int sl = sphys ^ ((row ^ (row >> 2)) & 3);
      __builtin_amdgcn_global_load_lds(
          (gu32*)(B + (size_t)(n0 + row) * 768 + kt * 32 + sl * 8),
          (lu32*)(&lsB[bf][seg * 512]), 16, 0, 0);
    }
    if (w < 2) {                             // B segs 8,9
      int seg = 8 + w;
      int row = seg * 16 + srow;
      int sl = sphys ^ ((row ^ (row >> 2)) & 3);
      __builtin_amdgcn_global_load_lds(
          (gu32*)(B + (size_t)(n0 + row) * 768 + kt * 32 + sl * 8),
          (lu32*)(&lsB[bf][seg * 512]), 16, 0, 0);
    }
  };

  stage(0, 0);
  #pragma unroll 1
  for (int kt = 0; kt < 24; ++kt) {
    int bf = kt & 1;
    if (kt < 23) {
      stage(kt + 1, bf ^ 1);                 // writes bf^1 (reads ended at prev barrier-2)
      if (w < 2) asm volatile("s_waitcnt vmcnt(5)" ::: "memory");  // own stage(kt)=5
      else       asm volatile("s_waitcnt vmcnt(4)" ::: "memory");  // own stage(kt)=4
    } else {
      asm volatile("s_waitcnt vmcnt(0)" ::: "memory");
    }
    __builtin_amdgcn_s_barrier();            // stage(kt) visible to all waves
    __builtin_amdgcn_sched_barrier(0);       // pin ds_reads below the barrier
    short8 af[4], bfv[5];
    #pragma unroll
    for (int f = 0; f < 4; ++f) {
      int row = wr * 64 + f * 16 + l15;
      int sl = lk ^ ((row ^ (row >> 2)) & 3);
      af[f] = *reinterpret_cast<const short8*>(&lsA[bf][row * 32 + sl * 8]);
    }
    #pragma unroll
    for (int f = 0; f < 5; ++f) {
      int rowb = wc * 80 + f * 16 + l15;
      int sl = lk ^ ((rowb ^ (rowb >> 2)) & 3);
      bfv[f] = *reinterpret_cast<const short8*>(&lsB[bf][rowb * 32 + sl * 8]);
    }
    #pragma unroll
    for (int fm = 0; fm < 4; ++fm)
      #pragma unroll
      for (int fn = 0; fn < 5; ++fn)
        acc[fm][fn] = __builtin_amdgcn_mfma_f32_16x16x32_bf16(af[fm], bfv[fn], acc[fm][fn], 0, 0, 0);
    __builtin_amdgcn_s_barrier();            // reads of bf done before stage(kt+2) overwrites
  }
  #pragma unroll
  for (int fm = 0; fm < 4; ++fm) {
    int mb = m0 + wr * 64 + fm * 16;
    int t = mb / 4000;
    int sq = mb - t * 4000;
    int cch = sq >> 4;
    #pragma unroll
    for (int fn = 0; fn < 5; ++fn) {
      int nb = n0 + wc * 80 + fn * 16;
      int nl = nb < 400 ? nb : nb - 400;
      int nq = (nb < 400 ? 0 : 25) + (nl >> 4);
      float bsv = bias[nb + l15];
      uint2 pk;
      pk.x = cvtpk(acc[fm][fn][0] + bsv, acc[fm][fn][1] + bsv);
      pk.y = cvtpk(acc[fm][fn][2] + bsv, acc[fm][fn][3] + bsv);
      *reinterpret_cast<uint2*>(
          &P[((((size_t)t * 250 + cch) * 50 + nq) << 8) + l15 * 16 + lk * 4]) = pk;
    }
  }
}

// ---------------- proj GEMM: +csT epilogue write ----------------

__global__ __launch_bounds__(256) void gemm_proj(
    const ushort_t* __restrict__ A, int lda,
    const ushort_t* __restrict__ B, int ldb,
    int M, int N, int KT,
    const float* __restrict__ bias,
    float* __restrict__ C, int ldc,
    ushort_t* __restrict__ C2,
    ushort_t* __restrict__ csT)        // [40][896][128]
{
  __shared__ __align__(16) ushort_t lsA[128 * 64];
  __shared__ __align__(16) ushort_t lsB[128 * 64];
  int bm = blockIdx.x, bn = blockIdx.y;
  int m0 = bm * 128, n0 = bn * 128;
  int tid = threadIdx.x, lane = tid & 63, w = tid >> 6;
  int wr = w >> 1, wc = w & 1;
  int l15 = lane & 15, lk = lane >> 4;
  f32x4 acc[4][4];
  #pragma unroll
  for (int i = 0; i < 4; ++i)
    #pragma unroll
    for (int j = 0; j < 4; ++j)
      #pragma unroll
      for (int r = 0; r < 4; ++r) acc[i][j][r] = 0.f;

  int r_in = lane >> 3, p = lane & 7;
  for (int kt = 0; kt < KT; ++kt) {
    __syncthreads();
    #pragma unroll
    for (int i = 0; i < 4; ++i) {
      int seg = w * 4 + i;
      int row = seg * 8 + r_in;
      int sl = p ^ (row & 7);
      int m = m0 + row;
      if (m < M)
        __builtin_amdgcn_global_load_lds(
            (gu32*)(A + (size_t)m * lda + kt * 64 + sl * 8),
            (lu32*)(lsA + seg * 512), 16, 0, 0);
      int n = n0 + row;
      if (n < N)
        __builtin_amdgcn_global_load_lds(
            (gu32*)(B + (size_t)n * ldb + kt * 64 + sl * 8),
            (lu32*)(lsB + seg * 512), 16, 0, 0);
    }
    __syncthreads();
    #pragma unroll
    for (int ks = 0; ks < 2; ++ks) {
      short8 af[4], bfv[4];
      #pragma unroll
      for (int f = 0; f < 4; ++f) {
        int row = wr * 64 + f * 16 + l15;
        af[f] = *reinterpret_cast<const short8*>(
            &lsA[row * 64 + (((ks * 4 + lk) ^ (row & 7)) << 3)]);
        int rowb = wc * 64 + f * 16 + l15;
        bfv[f] = *reinterpret_cast<const short8*>(
            &lsB[rowb * 64 + (((ks * 4 + lk) ^ (rowb & 7)) << 3)]);
      }
      #pragma unroll
      for (int fm = 0; fm < 4; ++fm)
        #pragma unroll
        for (int fn = 0; fn < 4; ++fn)
          acc[fm][fn] = __builtin_amdgcn_mfma_f32_16x16x32_bf16(af[fm], bfv[fn], acc[fm][fn], 0, 0, 0);
    }
  }
  #pragma unroll
  for (int fm = 0; fm < 4; ++fm)
    #pragma unroll
    for (int fn = 0; fn < 4; ++fn)
      #pragma unroll
      for (int r = 0; r < 4; ++r) {
        int m = m0 + wr * 64 + fm * 16 + lk * 4 + r;
        int n = n0 + wc * 64 + fn * 16 + l15;
        if (m < M && n < N) {
          float v = fmaxf(acc[fm][fn][r] + bias[n], 0.f);
          C[(size_t)m * ldc + n] = v;
          ushort_t vb = f2bf(v);
          C2[(size_t)m * ldc + n] = vb;
          int bq = m / 100, pq = m - bq * 100;     // m = b*100+p
          csT[((size_t)bq * 896 + n) * 128 + pq] = vb;
        }
      }
}

// ---------------- batched 128-tile MFMA GEMM ----------------
// EPI 10: splitK partial slab (f32). EPI 12: wcs->cat seg1+2 | probs.
// EPI 13: wctx -> cat seg3 = bf16(bert*v).

template <int EPI>
__global__ __launch_bounds__(256) void gemm128b(
    const ushort_t* __restrict__ A, long long sA, int lda,
    const ushort_t* __restrict__ Bm, long long sB, int ldb,
    int M, int N, int KT,
    float* __restrict__ Cf, ushort_t* __restrict__ Cb,
    const float* __restrict__ bertp, ushort_t* __restrict__ catp)
{
  __shared__ __align__(16) ushort_t lsA[128 * 64];
  __shared__ __align__(16) ushort_t lsB[128 * 64];
  int b = blockIdx.z;
  int koff = blockIdx.y * KT * 64;
  const ushort_t* Ab = A + (size_t)b * sA;
  const ushort_t* Bb = Bm + (size_t)b * sB;
  int n0 = blockIdx.x * 128;
  int tid = threadIdx.x, lane = tid & 63, w = tid >> 6;
  int wr = w >> 1, wc = w & 1;
  int l15 = lane & 15, lk = lane >> 4;
  f32x4 acc[4][4];
  #pragma unroll
  for (int i = 0; i < 4; ++i)
    #pragma unroll
    for (int j = 0; j < 4; ++j)
      #pragma unroll
      for (int r = 0; r < 4; ++r) acc[i][j][r] = 0.f;

  int r_in = lane >> 3, p = lane & 7;
  for (int kt = 0; kt < KT; ++kt) {
    __syncthreads();
    #pragma unroll
    for (int i = 0; i < 4; ++i) {
      int seg = w * 4 + i;
      int row = seg * 8 + r_in;
      int sl = p ^ (row & 7);
      if (row < M)
        __builtin_amdgcn_global_load_lds(
            (gu32*)(Ab + (size_t)row * lda + koff + kt * 64 + sl * 8),
            (lu32*)(lsA + seg * 512), 16, 0, 0);
      int n = n0 + row;
      if (n < N)
        __builtin_amdgcn_global_load_lds(
            (gu32*)(Bb + (size_t)n * ldb + koff + kt * 64 + sl * 8),
            (lu32*)(lsB + seg * 512), 16, 0, 0);
    }
    __syncthreads();
    #pragma unroll
    for (int ks = 0; ks < 2; ++ks) {
      short8 af[4], bfv[4];
      #pragma unroll
      for (int f = 0; f < 4; ++f) {
        int row = wr * 64 + f * 16 + l15;
        af[f] = *reinterpret_cast<const short8*>(
            &lsA[row * 64 + (((ks * 4 + lk) ^ (row & 7)) << 3)]);
        int rowb = wc * 64 + f * 16 + l15;
        bfv[f] = *reinterpret_cast<const short8*>(
            &lsB[rowb * 64 + (((ks * 4 + lk) ^ (rowb & 7)) << 3)]);
      }
      #pragma unroll
      for (int fm = 0; fm < 4; ++fm)
        #pragma unroll
        for (int fn = 0; fn < 4; ++fn)
          acc[fm][fn] = __builtin_amdgcn_mfma_f32_16x16x32_bf16(af[fm], bfv[fn], acc[fm][fn], 0, 0, 0);
    }
  }
  #pragma unroll
  for (int fm = 0; fm < 4; ++fm)
    #pragma unroll
    for (int fn = 0; fn < 4; ++fn)
      #pragma unroll
      for (int r = 0; r < 4; ++r) {
        int m = wr * 64 + fm * 16 + lk * 4 + r;
        int n = n0 + wc * 64 + fn * 16 + l15;
        if (m < M && n < N) {
          float v = acc[fm][fn][r];
          if (EPI == 10) {
            Cf[(size_t)blockIdx.y * 512000 + (size_t)b * 12800 + (size_t)m * 100 + n] = v;
          } else if (EPI == 12) {
            size_t row3 = ((size_t)b * 128 + m) * 3072;
            if (n < 768) {
              float bv = bertp[((size_t)b * 128 + m) * 768 + n];
              ushort_t wv = f2bf(v);
              catp[row3 + 768 + n] = wv;
              catp[row3 + 1536 + n] = f2bf(bv * bflo((u32)wv));
            } else {
              Cb[(size_t)b * 16384 + (size_t)m * 128 + (n - 768)] = f2bf(v);
            }
          } else {  // EPI 13
            float bv = bertp[((size_t)b * 128 + m) * 768 + n];
            catp[((size_t)b * 128 + m) * 3072 + 2304 + n] = f2bf(bv * v);
          }
        }
      }
}

// ---------------- attp GEMM: 64x128 tiles, counted-vmcnt dbuf pipeline ----------------

__global__ __launch_bounds__(256) void gemm64_attp(
    const ushort_t* __restrict__ A,     // cat [5120][3072]
    const ushort_t* __restrict__ B,     // attpw_bf [768][3072]
    const float* __restrict__ bias,
    const float* __restrict__ resid,    // bert
    float* __restrict__ C)              // d_out [5120][768]
{
  __shared__ __align__(16) ushort_t lsA[2][64 * 64];    // 16 KB
  __shared__ __align__(16) ushort_t lsB[2][128 * 64];   // 32 KB
  int bid = blockIdx.x;                 // 480 = 8*60
  int xcd = bid & 7, slot = bid >> 3;
  int L = xcd * 60 + slot;
  int bm = L / 6, bn = L - bm * 6;
  int m0 = bm * 64, n0 = bn * 128;
  int tid = threadIdx.x, lane = tid & 63, w = tid >> 6;
  int wr = w >> 1, wc = w & 1;
  int l15 = lane & 15, lk = lane >> 4;
  f32x4 acc[2][4];
  #pragma unroll
  for (int i = 0; i < 2; ++i)
    #pragma unroll
    for (int j = 0; j < 4; ++j)
      #pragma unroll
      for (int r = 0; r < 4; ++r) acc[i][j][r] = 0.f;

  int r_in = lane >> 3, p = lane & 7;
  auto stage = [&](int kt, int bf) {    // 6 vmem instructions per wave
    #pragma unroll
    for (int i = 0; i < 2; ++i) {
      int seg = w * 2 + i;
      int row = seg * 8 + r_in;
      int sl = p ^ (row & 7);
      __builtin_amdgcn_global_load_lds(
          (gu32*)(A + (size_t)(m0 + row) * 3072 + kt * 64 + sl * 8),
          (lu32*)(&lsA[bf][seg * 512]), 16, 0, 0);
    }
    #pragma unroll
    for (int i = 0; i < 4; ++i) {
      int seg = w * 4 + i;
      int row = seg * 8 + r_in;
      int sl = p ^ (row & 7);
      __builtin_amdgcn_global_load_lds(
          (gu32*)(B + (size_t)(n0 + row) * 3072 + kt * 64 + sl * 8),
          (lu32*)(&lsB[bf][seg * 512]), 16, 0, 0);
    }
  };

  stage(0, 0);
  #pragma unroll 1
  for (int kt = 0; kt < 48; ++kt) {
    int bf = kt & 1;
    if (kt < 47) {
      stage(kt + 1, bf ^ 1);
      asm volatile("s_waitcnt vmcnt(6)" ::: "memory");
    } else {
      asm volatile("s_waitcnt vmcnt(0)" ::: "memory");
    }
    __builtin_amdgcn_s_barrier();
    __builtin_amdgcn_sched_barrier(0);
    #pragma unroll
    for (int ks = 0; ks < 2; ++ks) {
      short8 af[2], bfv[4];
      #pragma unroll
      for (int f = 0; f < 2; ++f) {
        int row = wr * 32 + f * 16 + l15;
        af[f] = *reinterpret_cast<const short8*>(
            &lsA[bf][row * 64 + (((ks * 4 + lk) ^ (row & 7)) << 3)]);
      }
      #pragma unroll
      for (int f = 0; f < 4; ++f) {
        int rowb = wc * 64 + f * 16 + l15;
        bfv[f] = *reinterpret_cast<const short8*>(
            &lsB[bf][rowb * 64 + (((ks * 4 + lk) ^ (rowb & 7)) << 3)]);
      }
      #pragma unroll
      for (int fm = 0; fm < 2; ++fm)
        #pragma unroll
        for (int fn = 0; fn < 4; ++fn)
          acc[fm][fn] = __builtin_amdgcn_mfma_f32_16x16x32_bf16(af[fm], bfv[fn], acc[fm][fn], 0, 0, 0);
    }
    __builtin_amdgcn_s_barrier();
  }
  #pragma unroll
  for (int fm = 0; fm < 2; ++fm)
    #pragma unroll
    for (int fn = 0; fn < 4; ++fn)
      #pragma unroll
      for (int r = 0; r < 4; ++r) {
        int m = m0 + wr * 32 + fm * 16 + lk * 4 + r;
        int n = n0 + wc * 64 + fn * 16 + l15;
        float v = fmaxf(acc[fm][fn][r] + bias[n], 0.f) + resid[(size_t)m * 768 + n];
        C[(size_t)m * 768 + n] = v;
      }
}

// ---------------- fused biLSTM recurrence ----------------

__global__ __launch_bounds__(256) void lstm_recur(
    const ushort_t* __restrict__ pre,    // [20][250][50][256] bf16
    const ushort_t* __restrict__ whh,    // [2][400][128] bf16 (k-padded)
    ushort_t* __restrict__ hcat)         // [4000][256] bf16
{
  __shared__ __align__(16) ushort_t gx[25 * 256];
  __shared__ __align__(16) ushort_t h_lds[16 * 128];

  int dir = blockIdx.y;
  int c = blockIdx.x;
  int tid = threadIdx.x, lane = tid & 63, w = tid >> 6;
  int s = lane & 15, lk = lane >> 4;

  short8 wf[7][4];
  #pragma unroll
  for (int qi = 0; qi < 7; ++qi) {
    int q = w + qi * 4;
    if (q < 25) {
      const ushort_t* wp = whh + ((size_t)dir * 400 + q * 16 + s) * 128;
      #pragma unroll
      for (int ks = 0; ks < 4; ++ks)
        wf[qi][ks] = *reinterpret_cast<const short8*>(wp + ks * 32 + lk * 8);
    }
  }
  for (int e = tid; e < 1024; e += 256)
    *reinterpret_cast<u32*>(&h_lds[e * 2]) = 0u;

  float cst[2][4];
  #pragma unroll
  for (int g = 0; g < 2; ++g)
    #pragma unroll
    for (int r = 0; r < 4; ++r) cst[g][r] = 0.f;

  uint2 pvA[7], pvB[7];
  {
    int tt0 = dir ? 19 : 0;
    const ushort_t* pb = pre + ((((size_t)tt0 * 250 + c) * 50 + dir * 25) << 8);
    #pragma unroll
    for (int qi = 0; qi < 7; ++qi) {
      int q = w + qi * 4;
      if (q < 25) pvA[qi] = *reinterpret_cast<const uint2*>(pb + (q << 8) + s * 16 + lk * 4);
    }
  }
  __syncthreads();

  auto step = [&](uint2 (&pvc)[7], uint2 (&pvn)[7], int t) {
    f32x4 acc[7];
    #pragma unroll
    for (int qi = 0; qi < 7; ++qi)
      #pragma unroll
      for (int r = 0; r < 4; ++r) acc[qi][r] = 0.f;
    #pragma unroll
    for (int ks = 0; ks < 4; ++ks) {
      short8 af = *reinterpret_cast<const short8*>(
          &h_lds[s * 128 + (((ks * 4 + lk) ^ s) << 3)]);
      #pragma unroll
      for (int qi = 0; qi < 7; ++qi)
        if (w + qi * 4 < 25)
          acc[qi] = __builtin_amdgcn_mfma_f32_16x16x32_bf16(af, wf[qi][ks], acc[qi], 0, 0, 0);
    }
    #pragma unroll
    for (int qi = 0; qi < 7; ++qi)
      if (w + qi * 4 < 25) {
        acc[qi][0] += bflo(pvc[qi].x); acc[qi][1] += bfhi(pvc[qi].x);
        acc[qi][2] += bflo(pvc[qi].y); acc[qi][3] += bfhi(pvc[qi].y);
      }
    if (t + 1 < 20) {
      int tn = dir ? 19 - (t + 1) : (t + 1);
      const ushort_t* pb = pre + ((((size_t)tn * 250 + c) * 50 + dir * 25) << 8);
      #pragma unroll
      for (int qi = 0; qi < 7; ++qi) {
        int q = w + qi * 4;
        if (q < 25) pvn[qi] = *reinterpret_cast<const uint2*>(pb + (q << 8) + s * 16 + lk * 4);
      }
    }
    #pragma unroll
    for (int qi = 0; qi < 7; ++qi) {
      int q = w + qi * 4;
      if (q < 25) {
        ushort4 pk;
        pk.x = f2bf(acc[qi][0]); pk.y = f2bf(acc[qi][1]);
        pk.z = f2bf(acc[qi][2]); pk.w = f2bf(acc[qi][3]);
        *reinterpret_cast<ushort4*>(&gx[(q << 8) + s * 16 + lk * 4]) = pk;
      }
    }
    __syncthreads();
    #pragma unroll
    for (int gd = 0; gd < 2; ++gd) {
      int gi = w + gd * 4;
      if (gi < 7) {
        int j = gi * 16 + s;
        if (j < 100) {
          auto ld2 = [&](int q, int sp) {
            return *reinterpret_cast<const uint2*>(&gx[(q << 8) + sp * 16 + lk * 4]);
          };
          uint2 iv = ld2(gi, s);
          uint2 fv = (s < 12) ? ld2(6 + gi, s + 4) : ld2(7 + gi, s - 12);
          uint2 gv = (s < 8) ? ld2(12 + gi, s + 8) : ld2(13 + gi, s - 8);
          uint2 ov = (s < 4) ? ld2(18 + gi, s + 12) : ld2(19 + gi, s - 4);
          float ia[4] = {bflo(iv.x), bfhi(iv.x), bflo(iv.y), bfhi(iv.y)};
          float fa[4] = {bflo(fv.x), bfhi(fv.x), bflo(fv.y), bfhi(fv.y)};
          float ga[4] = {bflo(gv.x), bfhi(gv.x), bflo(gv.y), bfhi(gv.y)};
          float oa[4] = {bflo(ov.x), bfhi(ov.x), bflo(ov.y), bfhi(ov.y)};
          #pragma unroll
          for (int r = 0; r < 4; ++r) {
            float cc = sigm(fa[r]) * cst[gd][r] + sigm(ia[r]) * tanh_f(ga[r]);
            cst[gd][r] = cc;
            int row = lk * 4 + r;
            h_lds[row * 128 + (((j >> 3) ^ row) << 3) + (j & 7)] =
                f2bf(sigm(oa[r]) * tanh_f(cc));
          }
        }
      }
    }
    __syncthreads();
  };

  #pragma unroll 1
  for (int tp = 0; tp < 10; ++tp) {
    step(pvA, pvB, 2 * tp);
    step(pvB, pvA, 2 * tp + 1);
  }

  {
    int row = tid >> 4, sl = tid & 15;
    uint2 v = *reinterpret_cast<const uint2*>(&h_lds[row * 128 + ((sl ^ row) << 3)]);
    *reinterpret_cast<uint2*>(&hcat[(size_t)(c * 16 + row) * 256 + dir * 128 + sl * 8]) = v;
  }
}

// ---------------- small kernels ----------------

__global__ void rowdot_cs(const float* __restrict__ cs,
                          const float* __restrict__ W2w, const float* __restrict__ W2b,
                          float* __restrict__ part2) {
  int row = blockIdx.x * 4 + (threadIdx.x >> 6);
  int lane = threadIdx.x & 63;
  const float* x = cs + (size_t)row * 768;
  float s = 0.f;
  for (int k = lane; k < 768; k += 64) s += x[k] * W2w[k];
  for (int off = 32; off; off >>= 1) s += __shfl_down(s, off);
  if (lane == 0) part2[row] = s + W2b[0];
}

__global__ void softmax_both(const float* __restrict__ t4,   // [4][40][128][100]
                             const float* __restrict__ part1,
                             const float* __restrict__ part2,
                             const int* __restrict__ amask,
                             const int* __restrict__ cmask,
                             ushort_t* __restrict__ csatt,
                             ushort_t* __restrict__ csTcat) {
  int bid = blockIdx.x;
  int lane = threadIdx.x;
  auto tsum = [&](size_t idx) {
    return t4[idx] + t4[idx + 512000] + t4[idx + 1024000] + t4[idx + 1536000];
  };
  if (bid < 5120) {
    int b = bid >> 7;
    size_t base = (size_t)bid * 100;
    float e0 = tsum(base + lane) + part2[b * 100 + lane]
               + (1.f - (float)cmask[b * 100 + lane]) * -10000.f;
    bool has1 = (lane + 64) < 100;
    float e1 = -3.4e38f;
    if (has1)
      e1 = tsum(base + lane + 64) + part2[b * 100 + lane + 64]
           + (1.f - (float)cmask[b * 100 + lane + 64]) * -10000.f;
    float m = fmaxf(e0, e1);
    for (int off = 32; off; off >>= 1) m = fmaxf(m, __shfl_xor(m, off));
    float s0 = expf(e0 - m), s1 = has1 ? expf(e1 - m) : 0.f;
    float s = s0 + s1;
    for (int off = 32; off; off >>= 1) s += __shfl_xor(s, off);
    float inv = 1.f / s;
    csatt[(size_t)bid * 128 + lane] = f2bf(s0 * inv);
    csatt[(size_t)bid * 128 + lane + 64] = has1 ? f2bf(s1 * inv) : (ushort_t)0;
  } else {
    int idx = bid - 5120;
    int b = idx / 100, p = idx - b * 100;
    size_t base = (size_t)b * 12800 + p;
    int t0 = lane, t1 = lane + 64;
    float e0 = tsum(base + (size_t)t0 * 100) + part1[b * 128 + t0]
               + (1.f - (float)amask[b * 128 + t0]) * -10000.f;
    float e1 = tsum(base + (size_t)t1 * 100) + part1[b * 128 + t1]
               + (1.f - (float)amask[b * 128 + t1]) * -10000.f;
    float m = fmaxf(e0, e1);
    for (int off = 32; off; off >>= 1) m = fmaxf(m, __shfl_xor(m, off));
    float s0 = expf(e0 - m), s1 = expf(e1 - m);
    float s = s0 + s1;
    for (int off = 32; off; off >>= 1) s += __shfl_xor(s, off);
    float inv = 1.f / s;
    csTcat[((size_t)b * 896 + 768 + t0) * 128 + p] = f2bf(s0 * inv);
    csTcat[((size_t)b * 896 + 768 + t1) * 128 + p] = f2bf(s1 * inv);
  }
}

__global__ __launch_bounds__(256) void layernorm(float* __restrict__ X,
                                                 const float* __restrict__ w,
                                                 const float* __restrict__ bta) {
  int row = blockIdx.x;
  float* x = X + (size_t)row * 768;
  int t = threadIdx.x;
  float v[3];
  float s = 0.f;
  #pragma unroll
  for (int i = 0; i < 3; ++i) { v[i] = x[t + 256 * i]; s += v[i]; }
  __shared__ float red[256];
  red[t] = s; __syncthreads();
  for (int off = 128; off; off >>= 1) { if (t < off) red[t] += red[t + off]; __syncthreads(); }
  float mean = red[0] * (1.f / 768.f);
  __syncthreads();
  float q = 0.f;
  #pragma unroll
  for (int i = 0; i < 3; ++i) { float d = v[i] - mean; q += d * d; }
  red[t] = q; __syncthreads();
  for (int off = 128; off; off >>= 1) { if (t < off) red[t] += red[t + off]; __syncthreads(); }
  float inv = rsqrtf(red[0] * (1.f / 768.f) + 1e-12f);
  #pragma unroll
  for (int i = 0; i < 3; ++i) {
    int k = t + 256 * i;
    x[k] = w[k] * ((v[i] - mean) * inv) + bta[k];
  }
}

// ---------------- host orchestration ----------------

extern "C" void kernel_launch(void* const* d_in, const int* in_sizes, int n_in,
                              void* d_out, int out_size, void* d_ws, size_t ws_size,
                              hipStream_t stream) {
  (void)in_sizes; (void)n_in; (void)out_size; (void)ws_size;
  const float* bert  = (const float*)d_in[0];
  const float* cmn   = (const float*)d_in[1];
  const int*   amask = (const int*)d_in[2];
  const int*   cmask = (const int*)d_in[3];
  const float* Wih_f = (const float*)d_in[8];
  const float* Whh_f = (const float*)d_in[9];
  const float* bih_f = (const float*)d_in[10];
  const float* bhh_f = (const float*)d_in[11];
  const float* Wih_b = (const float*)d_in[12];
  const float* Whh_b = (const float*)d_in[13];
  const float* bih_b = (const float*)d_in[14];
  const float* bhh_b = (const float*)d_in[15];
  const float* projW = (const float*)d_in[16];
  const float* projb = (const float*)d_in[17];
  const float* W1w   = (const float*)d_in[18];
  const float* W1b   = (const float*)d_in[19];
  const float* W2w   = (const float*)d_in[20];
  const float* W2b   = (const float*)d_in[21];
  const float* W3    = (const float*)d_in[22];
  const float* attpW = (const float*)d_in[23];
  const float* attpb = (const float*)d_in[24];
  const float* lnw   = (const float*)d_in[25];
  const float* lnb   = (const float*)d_in[26];

  char* base = (char*)d_ws;
  size_t off = 0;
  auto alloc = [&](size_t bytes) -> char* {
    char* r = base + off;
    off += (bytes + 255) & ~(size_t)255;
    return r;
  };
  ushort_t* wihcat   = (ushort_t*)alloc(800 * 768 * 2);
  ushort_t* whhcat   = (ushort_t*)alloc(800 * 128 * 2);
  float*    biascat  = (float*)alloc(800 * 4);
  ushort_t* projw_bf = (ushort_t*)alloc(768 * 256 * 2);
  ushort_t* attpw_bf = (ushort_t*)alloc(768 * 3072 * 2);
  ushort_t* hcat     = (ushort_t*)alloc(4000 * 256 * 2);
  float*    cs       = (float*)alloc((size_t)4000 * 768 * 4);
  ushort_t* cs_bf    = (ushort_t*)alloc((size_t)4000 * 768 * 2);
  ushort_t* csTcat   = (ushort_t*)alloc((size_t)40 * 896 * 128 * 2);
  float*    part1    = (float*)alloc(5120 * 4);
  float*    part2    = (float*)alloc(4000 * 4);
  float*    total4   = (float*)alloc((size_t)4 * 40 * 128 * 100 * 4);
  ushort_t* csatt_bf = (ushort_t*)alloc((size_t)40 * 128 * 128 * 2);
  ushort_t* probs_bf = (ushort_t*)alloc((size_t)40 * 128 * 128 * 2);
  ushort_t* bw3_bf   = (ushort_t*)alloc((size_t)40 * 128 * 768 * 2);
  ushort_t* bertT    = (ushort_t*)alloc((size_t)40 * 768 * 128 * 2);
  ushort_t* cat      = (ushort_t*)alloc((size_t)5120 * 3072 * 2);
  ushort_t* x_bf     = (ushort_t*)alloc((size_t)20 * 4000 * 768 * 2);
  ushort_t* pre      = (ushort_t*)alloc((size_t)20 * 250 * 50 * 256 * 2);

  // fused prep: weights | bert (bw3/bT/cat seg0) | x convert | part1
  prep_all<<<4320, 256, 0, stream>>>(
      Wih_f, Wih_b, Whh_f, Whh_b, bih_f, bhh_f, bih_b, bhh_b, projW, attpW,
      wihcat, whhcat, biascat, projw_bf, attpw_bf,
      bert, W3, bw3_bf, bertT, cat,
      (const float4*)cmn, x_bf,
      W1w, W1b, part1);

  // pre = x @ Wih^T + (bih+bhh): 128x160 tiles, BK=32, 4 blocks/CU, XCD-chunked
  gemm_pre32<<<3125, 256, 0, stream>>>(x_bf, wihcat, biascat, pre);
  lstm_recur<<<dim3(250, 2), 256, 0, stream>>>(pre, whhcat, hcat);

  // cs = relu(hcat @ projW^T + projb): f32 + bf16 + csT (transposed)
  gemm_proj<<<dim3(32, 6), 256, 0, stream>>>(hcat, 256, projw_bf, 256, 4000, 768, 4,
                                             projb, cs, 768, cs_bf, csTcat);
  rowdot_cs<<<1000, 256, 0, stream>>>(cs, W2w, W2b, part2);

  // total partials: (W3*bert) @ cs^T, splitK=4
  gemm128b<10><<<dim3(1, 4, 40), 256, 0, stream>>>(
      bw3_bf, 98304LL, 768, cs_bf, 76800LL, 768, 128, 100, 3,
      total4, nullptr, nullptr, nullptr);
  softmax_both<<<9120, 64, 0, stream>>>(total4, part1, part2, amask, cmask,
                                        csatt_bf, csTcat);
  // merged: [wcs -> cat seg1+seg2 | probs] = cs_att @ [csT; ctx_att]
  gemm128b<12><<<dim3(7, 1, 40), 256, 0, stream>>>(
      csatt_bf, 16384LL, 128, csTcat, 114688LL, 128, 128, 896, 2,
      nullptr, probs_bf, bert, cat);
  // wctx -> cat seg3 = bf16(bert * probs@bertT)
  gemm128b<13><<<dim3(6, 1, 40), 256, 0, stream>>>(
      probs_bf, 16384LL, 128, bertT, 98304LL, 128, 128, 768, 2,
      nullptr, nullptr, bert, cat);

  // x = relu(cat @ attpW^T + attpb) + bert -> d_out, then LN in place
  gemm64_attp<<<480, 256, 0, stream>>>(cat, attpw_bf, attpb, bert, (float*)d_out);
  layernorm<<<5120, 256, 0, stream>>>((float*)d_out, lnw, lnb);
}

// Round 20
// 479.266 us; speedup vs baseline: 1.0505x; 1.0505x over previous
//
#include <hip/hip_runtime.h>

// QANet attention layer on MI355X (gfx950).
// B=40,S=128,H=768, NP=100, PL=20, HID=100, N=4000 sequences.
// Round 20: REVERT to r18 (best verified: 481.1/481.3 us, absmax 0.03125).
// r19's BK=32 occupancy experiment was falsified (170 us: bank conflicts
// 1.08e7 from a wrong 32-col swizzle + occupancy did not rise + 2x barrier
// overhead). Converged structure:
//  - prep_all: weights|bert-derived|x-convert|part1 in one launch
//  - gemm_pre160: 128x160 DMA GEMM, counted-vmcnt dbuf, XCD-chunked
//  - lstm_recur: fused 20-step biLSTM, Whh in VGPRs, LDS gate exchange
//  - gemm_proj (+bf16+csT epilogue), rowdot_cs
//  - splitK=4 total GEMM + merged dual softmax
//  - gemm128b<12> (wcs|probs merged, cat epilogue), <13> (wctx epilogue)
//  - gemm64_attp (counted-vmcnt dbuf) + layernorm

typedef unsigned short ushort_t;
typedef unsigned int u32;
typedef __attribute__((ext_vector_type(8))) short short8;
typedef __attribute__((ext_vector_type(4))) float f32x4;
typedef __attribute__((address_space(1))) const u32 gu32;
typedef __attribute__((address_space(3))) u32 lu32;

__device__ __forceinline__ ushort_t f2bf(float f) {
  u32 x = __builtin_bit_cast(u32, f);
  u32 r = (x + 0x7fffu + ((x >> 16) & 1u)) >> 16;
  return (ushort_t)r;
}
__device__ __forceinline__ float bflo(u32 u) { return __builtin_bit_cast(float, u << 16); }
__device__ __forceinline__ float bfhi(u32 u) { return __builtin_bit_cast(float, u & 0xffff0000u); }
__device__ __forceinline__ u32 cvtpk(float lo, float hi) {
  u32 r;
  asm("v_cvt_pk_bf16_f32 %0, %1, %2" : "=v"(r) : "v"(lo), "v"(hi));
  return r;
}

__device__ __forceinline__ float sigm(float x) { return 1.f / (1.f + __expf(-x)); }
__device__ __forceinline__ float tanh_f(float x) { return 1.f - 2.f / (__expf(2.f * x) + 1.f); }

// ---------------- fused prep: weights | bert-derived | convert | part1 ----------------

__global__ __launch_bounds__(256) void prep_all(
    const float* __restrict__ Wih_f, const float* __restrict__ Wih_b,
    const float* __restrict__ Whh_f, const float* __restrict__ Whh_b,
    const float* __restrict__ bih_f, const float* __restrict__ bhh_f,
    const float* __restrict__ bih_b, const float* __restrict__ bhh_b,
    const float* __restrict__ projW, const float* __restrict__ attpW,
    ushort_t* __restrict__ wihcat, ushort_t* __restrict__ whhcat,
    float* __restrict__ biascat, ushort_t* __restrict__ projw_bf,
    ushort_t* __restrict__ attpw_bf,
    const float* __restrict__ bert, const float* __restrict__ W3,
    ushort_t* __restrict__ bw3, ushort_t* __restrict__ bT, ushort_t* __restrict__ cat,
    const float4* __restrict__ x4, ushort_t* __restrict__ xb,
    const float* __restrict__ W1w, const float* __restrict__ W1b,
    float* __restrict__ part1)
{
  __shared__ ushort_t tl[64 * 130];
  int bid = blockIdx.x, tid = threadIdx.x;
  if (bid < 512) {
    const int TOT = 614400 + 102400 + 800 + 196608 + 2359296;
    for (int idx = bid * 256 + tid; idx < TOT; idx += 512 * 256) {
      if (idx < 614400) {                       // Wih cat [800][768]
        int g = idx / 768, k = idx % 768;
        float v = g < 400 ? Wih_f[g * 768 + k] : Wih_b[(g - 400) * 768 + k];
        wihcat[idx] = f2bf(v);
      } else if (idx < 716800) {                // Whh cat padded [2][400][128]
        int e = idx - 614400; int g = e / 128, j = e % 128;
        float v = 0.f;
        if (j < 100) v = g < 400 ? Whh_f[g * 100 + j] : Whh_b[(g - 400) * 100 + j];
        whhcat[e] = f2bf(v);
      } else if (idx < 717600) {                // bias cat [800]
        int g = idx - 716800;
        biascat[g] = g < 400 ? bih_f[g] + bhh_f[g] : bih_b[g - 400] + bhh_b[g - 400];
      } else if (idx < 914208) {                // projW padded [768][256]
        int e = idx - 717600; int o = e / 256, j = e % 256;
        float v = 0.f;
        if (j < 100) v = projW[o * 200 + j];
        else if (j >= 128 && j < 228) v = projW[o * 200 + 100 + (j - 128)];
        projw_bf[e] = f2bf(v);
      } else {                                  // attpW [768][3072]
        int e = idx - 914208;
        attpw_bf[e] = f2bf(attpW[e]);
      }
    }
  } else if (bid < 992) {
    int e0 = bid - 512;
    int ht = e0 % 12, b = e0 / 12;
    int h0 = ht * 64;
    for (int e = tid; e < 8192; e += 256) {
      int t = e >> 6, hh = e & 63;
      float v = bert[((size_t)b * 128 + t) * 768 + h0 + hh];
      ushort_t vb = f2bf(v);
      bw3[((size_t)b * 128 + t) * 768 + h0 + hh] = f2bf(v * W3[h0 + hh]);
      cat[((size_t)b * 128 + t) * 3072 + h0 + hh] = vb;
      tl[hh * 130 + t] = vb;
    }
    __syncthreads();
    for (int e = tid; e < 8192; e += 256) {
      int hh = e >> 7, t = e & 127;
      bT[((size_t)b * 768 + h0 + hh) * 128 + t] = tl[hh * 130 + t];
    }
  } else if (bid < 3040) {
    for (int i = (bid - 992) * 256 + tid; i < 15360000; i += 2048 * 256) {
      int seq = i / 3840;
      int rem = i - seq * 3840;
      int t = rem / 192;
      int k4 = rem - t * 192;
      float4 v = x4[i];
      ushort4 o;
      o.x = f2bf(v.x); o.y = f2bf(v.y); o.z = f2bf(v.z); o.w = f2bf(v.w);
      *reinterpret_cast<ushort4*>(&xb[((size_t)t * 4000 + seq) * 768 + k4 * 4]) = o;
    }
  } else {
    int row = (bid - 3040) * 4 + (tid >> 6);
    int lane = tid & 63;
    const float* x = bert + (size_t)row * 768;
    float s = 0.f;
    for (int k = lane; k < 768; k += 64) s += x[k] * W1w[k];
    for (int off = 32; off; off >>= 1) s += __shfl_down(s, off);
    if (lane == 0) part1[row] = s + W1b[0];
  }
}

// ---------------- pre GEMM: 128x160 tiles, counted-vmcnt dbuf pipeline ----------------

__global__ __launch_bounds__(256) void gemm_pre160(
    const ushort_t* __restrict__ A,     // x_bf [20][4000][768]
    const ushort_t* __restrict__ B,     // wihcat [800][768]
    const float* __restrict__ bias,
    ushort_t* __restrict__ P)
{
  __shared__ __align__(16) ushort_t lsA[2][128 * 64];   // 32 KB
  __shared__ __align__(16) ushort_t lsB[2][160 * 64];   // 40 KB
  int bid = blockIdx.x;
  int xcd = bid & 7, slot = bid >> 3;
  int L = (xcd < 5) ? xcd * 391 + slot : 1955 + (xcd - 5) * 390 + slot;
  int bm = L / 5, bn = L - bm * 5;
  int m0 = bm * 128, n0 = bn * 160;
  int tid = threadIdx.x, lane = tid & 63, w = tid >> 6;
  int wr = w >> 1, wc = w & 1;
  int l15 = lane & 15, lk = lane >> 4;
  f32x4 acc[4][5];
  #pragma unroll
  for (int i = 0; i < 4; ++i)
    #pragma unroll
    for (int j = 0; j < 5; ++j)
      #pragma unroll
      for (int r = 0; r < 4; ++r) acc[i][j][r] = 0.f;

  int r_in = lane >> 3, p = lane & 7;
  auto stage = [&](int kt, int bf) {    // 9 vmem instructions per wave
    #pragma unroll
    for (int i = 0; i < 4; ++i) {
      int seg = w * 4 + i;
      int row = seg * 8 + r_in;
      int sl = p ^ (row & 7);
      __builtin_amdgcn_global_load_lds(
          (gu32*)(A + (size_t)(m0 + row) * 768 + kt * 64 + sl * 8),
          (lu32*)(&lsA[bf][seg * 512]), 16, 0, 0);
    }
    #pragma unroll
    for (int i = 0; i < 5; ++i) {
      int seg = w * 5 + i;
      int row = seg * 8 + r_in;
      int sl = p ^ (row & 7);
      __builtin_amdgcn_global_load_lds(
          (gu32*)(B + (size_t)(n0 + row) * 768 + kt * 64 + sl * 8),
          (lu32*)(&lsB[bf][seg * 512]), 16, 0, 0);
    }
  };

  stage(0, 0);
  #pragma unroll 1
  for (int kt = 0; kt < 12; ++kt) {
    int bf = kt & 1;
    if (kt < 11) {
      stage(kt + 1, bf ^ 1);            // writes bf^1 (reads ended at prev barrier-2)
      asm volatile("s_waitcnt vmcnt(9)" ::: "memory");   // waits ONLY stage(kt)
    } else {
      asm volatile("s_waitcnt vmcnt(0)" ::: "memory");
    }
    __builtin_amdgcn_s_barrier();       // stage(kt) visible to all waves
    __builtin_amdgcn_sched_barrier(0);  // pin ds_reads below the barrier
    #pragma unroll
    for (int ks = 0; ks < 2; ++ks) {
      short8 af[4], bfv[5];
      #pragma unroll
      for (int f = 0; f < 4; ++f) {
        int row = wr * 64 + f * 16 + l15;
        af[f] = *reinterpret_cast<const short8*>(
            &lsA[bf][row * 64 + (((ks * 4 + lk) ^ (row & 7)) << 3)]);
      }
      #pragma unroll
      for (int f = 0; f < 5; ++f) {
        int rowb = wc * 80 + f * 16 + l15;
        bfv[f] = *reinterpret_cast<const short8*>(
            &lsB[bf][rowb * 64 + (((ks * 4 + lk) ^ (rowb & 7)) << 3)]);
      }
      #pragma unroll
      for (int fm = 0; fm < 4; ++fm)
        #pragma unroll
        for (int fn = 0; fn < 5; ++fn)
          acc[fm][fn] = __builtin_amdgcn_mfma_f32_16x16x32_bf16(af[fm], bfv[fn], acc[fm][fn], 0, 0, 0);
    }
    __builtin_amdgcn_s_barrier();       // reads of bf done before stage(kt+2) overwrites
  }
  #pragma unroll
  for (int fm = 0; fm < 4; ++fm) {
    int mb = m0 + wr * 64 + fm * 16;
    int t = mb / 4000;
    int sq = mb - t * 4000;
    int cch = sq >> 4;
    #pragma unroll
    for (int fn = 0; fn < 5; ++fn) {
      int nb = n0 + wc * 80 + fn * 16;
      int nl = nb < 400 ? nb : nb - 400;
      int nq = (nb < 400 ? 0 : 25) + (nl >> 4);
      float bsv = bias[nb + l15];
      uint2 pk;
      pk.x = cvtpk(acc[fm][fn][0] + bsv, acc[fm][fn][1] + bsv);
      pk.y = cvtpk(acc[fm][fn][2] + bsv, acc[fm][fn][3] + bsv);
      *reinterpret_cast<uint2*>(
          &P[((((size_t)t * 250 + cch) * 50 + nq) << 8) + l15 * 16 + lk * 4]) = pk;
    }
  }
}

// ---------------- proj GEMM: +csT epilogue write ----------------

__global__ __launch_bounds__(256) void gemm_proj(
    const ushort_t* __restrict__ A, int lda,
    const ushort_t* __restrict__ B, int ldb,
    int M, int N, int KT,
    const float* __restrict__ bias,
    float* __restrict__ C, int ldc,
    ushort_t* __restrict__ C2,
    ushort_t* __restrict__ csT)        // [40][896][128]
{
  __shared__ __align__(16) ushort_t lsA[128 * 64];
  __shared__ __align__(16) ushort_t lsB[128 * 64];
  int bm = blockIdx.x, bn = blockIdx.y;
  int m0 = bm * 128, n0 = bn * 128;
  int tid = threadIdx.x, lane = tid & 63, w = tid >> 6;
  int wr = w >> 1, wc = w & 1;
  int l15 = lane & 15, lk = lane >> 4;
  f32x4 acc[4][4];
  #pragma unroll
  for (int i = 0; i < 4; ++i)
    #pragma unroll
    for (int j = 0; j < 4; ++j)
      #pragma unroll
      for (int r = 0; r < 4; ++r) acc[i][j][r] = 0.f;

  int r_in = lane >> 3, p = lane & 7;
  for (int kt = 0; kt < KT; ++kt) {
    __syncthreads();
    #pragma unroll
    for (int i = 0; i < 4; ++i) {
      int seg = w * 4 + i;
      int row = seg * 8 + r_in;
      int sl = p ^ (row & 7);
      int m = m0 + row;
      if (m < M)
        __builtin_amdgcn_global_load_lds(
            (gu32*)(A + (size_t)m * lda + kt * 64 + sl * 8),
            (lu32*)(lsA + seg * 512), 16, 0, 0);
      int n = n0 + row;
      if (n < N)
        __builtin_amdgcn_global_load_lds(
            (gu32*)(B + (size_t)n * ldb + kt * 64 + sl * 8),
            (lu32*)(lsB + seg * 512), 16, 0, 0);
    }
    __syncthreads();
    #pragma unroll
    for (int ks = 0; ks < 2; ++ks) {
      short8 af[4], bfv[4];
      #pragma unroll
      for (int f = 0; f < 4; ++f) {
        int row = wr * 64 + f * 16 + l15;
        af[f] = *reinterpret_cast<const short8*>(
            &lsA[row * 64 + (((ks * 4 + lk) ^ (row & 7)) << 3)]);
        int rowb = wc * 64 + f * 16 + l15;
        bfv[f] = *reinterpret_cast<const short8*>(
            &lsB[rowb * 64 + (((ks * 4 + lk) ^ (rowb & 7)) << 3)]);
      }
      #pragma unroll
      for (int fm = 0; fm < 4; ++fm)
        #pragma unroll
        for (int fn = 0; fn < 4; ++fn)
          acc[fm][fn] = __builtin_amdgcn_mfma_f32_16x16x32_bf16(af[fm], bfv[fn], acc[fm][fn], 0, 0, 0);
    }
  }
  #pragma unroll
  for (int fm = 0; fm < 4; ++fm)
    #pragma unroll
    for (int fn = 0; fn < 4; ++fn)
      #pragma unroll
      for (int r = 0; r < 4; ++r) {
        int m = m0 + wr * 64 + fm * 16 + lk * 4 + r;
        int n = n0 + wc * 64 + fn * 16 + l15;
        if (m < M && n < N) {
          float v = fmaxf(acc[fm][fn][r] + bias[n], 0.f);
          C[(size_t)m * ldc + n] = v;
          ushort_t vb = f2bf(v);
          C2[(size_t)m * ldc + n] = vb;
          int bq = m / 100, pq = m - bq * 100;     // m = b*100+p
          csT[((size_t)bq * 896 + n) * 128 + pq] = vb;
        }
      }
}

// ---------------- batched 128-tile MFMA GEMM ----------------
// EPI 10: splitK partial slab (f32). EPI 12: wcs->cat seg1+2 | probs.
// EPI 13: wctx -> cat seg3 = bf16(bert*v).

template <int EPI>
__global__ __launch_bounds__(256) void gemm128b(
    const ushort_t* __restrict__ A, long long sA, int lda,
    const ushort_t* __restrict__ Bm, long long sB, int ldb,
    int M, int N, int KT,
    float* __restrict__ Cf, ushort_t* __restrict__ Cb,
    const float* __restrict__ bertp, ushort_t* __restrict__ catp)
{
  __shared__ __align__(16) ushort_t lsA[128 * 64];
  __shared__ __align__(16) ushort_t lsB[128 * 64];
  int b = blockIdx.z;
  int koff = blockIdx.y * KT * 64;
  const ushort_t* Ab = A + (size_t)b * sA;
  const ushort_t* Bb = Bm + (size_t)b * sB;
  int n0 = blockIdx.x * 128;
  int tid = threadIdx.x, lane = tid & 63, w = tid >> 6;
  int wr = w >> 1, wc = w & 1;
  int l15 = lane & 15, lk = lane >> 4;
  f32x4 acc[4][4];
  #pragma unroll
  for (int i = 0; i < 4; ++i)
    #pragma unroll
    for (int j = 0; j < 4; ++j)
      #pragma unroll
      for (int r = 0; r < 4; ++r) acc[i][j][r] = 0.f;

  int r_in = lane >> 3, p = lane & 7;
  for (int kt = 0; kt < KT; ++kt) {
    __syncthreads();
    #pragma unroll
    for (int i = 0; i < 4; ++i) {
      int seg = w * 4 + i;
      int row = seg * 8 + r_in;
      int sl = p ^ (row & 7);
      if (row < M)
        __builtin_amdgcn_global_load_lds(
            (gu32*)(Ab + (size_t)row * lda + koff + kt * 64 + sl * 8),
            (lu32*)(lsA + seg * 512), 16, 0, 0);
      int n = n0 + row;
      if (n < N)
        __builtin_amdgcn_global_load_lds(
            (gu32*)(Bb + (size_t)n * ldb + koff + kt * 64 + sl * 8),
            (lu32*)(lsB + seg * 512), 16, 0, 0);
    }
    __syncthreads();
    #pragma unroll
    for (int ks = 0; ks < 2; ++ks) {
      short8 af[4], bfv[4];
      #pragma unroll
      for (int f = 0; f < 4; ++f) {
        int row = wr * 64 + f * 16 + l15;
        af[f] = *reinterpret_cast<const short8*>(
            &lsA[row * 64 + (((ks * 4 + lk) ^ (row & 7)) << 3)]);
        int rowb = wc * 64 + f * 16 + l15;
        bfv[f] = *reinterpret_cast<const short8*>(
            &lsB[rowb * 64 + (((ks * 4 + lk) ^ (rowb & 7)) << 3)]);
      }
      #pragma unroll
      for (int fm = 0; fm < 4; ++fm)
        #pragma unroll
        for (int fn = 0; fn < 4; ++fn)
          acc[fm][fn] = __builtin_amdgcn_mfma_f32_16x16x32_bf16(af[fm], bfv[fn], acc[fm][fn], 0, 0, 0);
    }
  }
  #pragma unroll
  for (int fm = 0; fm < 4; ++fm)
    #pragma unroll
    for (int fn = 0; fn < 4; ++fn)
      #pragma unroll
      for (int r = 0; r < 4; ++r) {
        int m = wr * 64 + fm * 16 + lk * 4 + r;
        int n = n0 + wc * 64 + fn * 16 + l15;
        if (m < M && n < N) {
          float v = acc[fm][fn][r];
          if (EPI == 10) {
            Cf[(size_t)blockIdx.y * 512000 + (size_t)b * 12800 + (size_t)m * 100 + n] = v;
          } else if (EPI == 12) {
            size_t row3 = ((size_t)b * 128 + m) * 3072;
            if (n < 768) {
              float bv = bertp[((size_t)b * 128 + m) * 768 + n];
              ushort_t wv = f2bf(v);
              catp[row3 + 768 + n] = wv;
              catp[row3 + 1536 + n] = f2bf(bv * bflo((u32)wv));
            } else {
              Cb[(size_t)b * 16384 + (size_t)m * 128 + (n - 768)] = f2bf(v);
            }
          } else {  // EPI 13
            float bv = bertp[((size_t)b * 128 + m) * 768 + n];
            catp[((size_t)b * 128 + m) * 3072 + 2304 + n] = f2bf(bv * v);
          }
        }
      }
}

// ---------------- attp GEMM: 64x128 tiles, counted-vmcnt dbuf pipeline ----------------

__global__ __launch_bounds__(256) void gemm64_attp(
    const ushort_t* __restrict__ A,     // cat [5120][3072]
    const ushort_t* __restrict__ B,     // attpw_bf [768][3072]
    const float* __restrict__ bias,
    const float* __restrict__ resid,    // bert
    float* __restrict__ C)              // d_out [5120][768]
{
  __shared__ __align__(16) ushort_t lsA[2][64 * 64];    // 16 KB
  __shared__ __align__(16) ushort_t lsB[2][128 * 64];   // 32 KB
  int bid = blockIdx.x;                 // 480 = 8*60
  int xcd = bid & 7, slot = bid >> 3;
  int L = xcd * 60 + slot;
  int bm = L / 6, bn = L - bm * 6;
  int m0 = bm * 64, n0 = bn * 128;
  int tid = threadIdx.x, lane = tid & 63, w = tid >> 6;
  int wr = w >> 1, wc = w & 1;
  int l15 = lane & 15, lk = lane >> 4;
  f32x4 acc[2][4];
  #pragma unroll
  for (int i = 0; i < 2; ++i)
    #pragma unroll
    for (int j = 0; j < 4; ++j)
      #pragma unroll
      for (int r = 0; r < 4; ++r) acc[i][j][r] = 0.f;

  int r_in = lane >> 3, p = lane & 7;
  auto stage = [&](int kt, int bf) {    // 6 vmem instructions per wave
    #pragma unroll
    for (int i = 0; i < 2; ++i) {
      int seg = w * 2 + i;
      int row = seg * 8 + r_in;
      int sl = p ^ (row & 7);
      __builtin_amdgcn_global_load_lds(
          (gu32*)(A + (size_t)(m0 + row) * 3072 + kt * 64 + sl * 8),
          (lu32*)(&lsA[bf][seg * 512]), 16, 0, 0);
    }
    #pragma unroll
    for (int i = 0; i < 4; ++i) {
      int seg = w * 4 + i;
      int row = seg * 8 + r_in;
      int sl = p ^ (row & 7);
      __builtin_amdgcn_global_load_lds(
          (gu32*)(B + (size_t)(n0 + row) * 3072 + kt * 64 + sl * 8),
          (lu32*)(&lsB[bf][seg * 512]), 16, 0, 0);
    }
  };

  stage(0, 0);
  #pragma unroll 1
  for (int kt = 0; kt < 48; ++kt) {
    int bf = kt & 1;
    if (kt < 47) {
      stage(kt + 1, bf ^ 1);
      asm volatile("s_waitcnt vmcnt(6)" ::: "memory");
    } else {
      asm volatile("s_waitcnt vmcnt(0)" ::: "memory");
    }
    __builtin_amdgcn_s_barrier();
    __builtin_amdgcn_sched_barrier(0);
    #pragma unroll
    for (int ks = 0; ks < 2; ++ks) {
      short8 af[2], bfv[4];
      #pragma unroll
      for (int f = 0; f < 2; ++f) {
        int row = wr * 32 + f * 16 + l15;
        af[f] = *reinterpret_cast<const short8*>(
            &lsA[bf][row * 64 + (((ks * 4 + lk) ^ (row & 7)) << 3)]);
      }
      #pragma unroll
      for (int f = 0; f < 4; ++f) {
        int rowb = wc * 64 + f * 16 + l15;
        bfv[f] = *reinterpret_cast<const short8*>(
            &lsB[bf][rowb * 64 + (((ks * 4 + lk) ^ (rowb & 7)) << 3)]);
      }
      #pragma unroll
      for (int fm = 0; fm < 2; ++fm)
        #pragma unroll
        for (int fn = 0; fn < 4; ++fn)
          acc[fm][fn] = __builtin_amdgcn_mfma_f32_16x16x32_bf16(af[fm], bfv[fn], acc[fm][fn], 0, 0, 0);
    }
    __builtin_amdgcn_s_barrier();
  }
  #pragma unroll
  for (int fm = 0; fm < 2; ++fm)
    #pragma unroll
    for (int fn = 0; fn < 4; ++fn)
      #pragma unroll
      for (int r = 0; r < 4; ++r) {
        int m = m0 + wr * 32 + fm * 16 + lk * 4 + r;
        int n = n0 + wc * 64 + fn * 16 + l15;
        float v = fmaxf(acc[fm][fn][r] + bias[n], 0.f) + resid[(size_t)m * 768 + n];
        C[(size_t)m * 768 + n] = v;
      }
}

// ---------------- fused biLSTM recurrence ----------------

__global__ __launch_bounds__(256) void lstm_recur(
    const ushort_t* __restrict__ pre,    // [20][250][50][256] bf16
    const ushort_t* __restrict__ whh,    // [2][400][128] bf16 (k-padded)
    ushort_t* __restrict__ hcat)         // [4000][256] bf16
{
  __shared__ __align__(16) ushort_t gx[25 * 256];
  __shared__ __align__(16) ushort_t h_lds[16 * 128];

  int dir = blockIdx.y;
  int c = blockIdx.x;
  int tid = threadIdx.x, lane = tid & 63, w = tid >> 6;
  int s = lane & 15, lk = lane >> 4;

  short8 wf[7][4];
  #pragma unroll
  for (int qi = 0; qi < 7; ++qi) {
    int q = w + qi * 4;
    if (q < 25) {
      const ushort_t* wp = whh + ((size_t)dir * 400 + q * 16 + s) * 128;
      #pragma unroll
      for (int ks = 0; ks < 4; ++ks)
        wf[qi][ks] = *reinterpret_cast<const short8*>(wp + ks * 32 + lk * 8);
    }
  }
  for (int e = tid; e < 1024; e += 256)
    *reinterpret_cast<u32*>(&h_lds[e * 2]) = 0u;

  float cst[2][4];
  #pragma unroll
  for (int g = 0; g < 2; ++g)
    #pragma unroll
    for (int r = 0; r < 4; ++r) cst[g][r] = 0.f;

  uint2 pvA[7], pvB[7];
  {
    int tt0 = dir ? 19 : 0;
    const ushort_t* pb = pre + ((((size_t)tt0 * 250 + c) * 50 + dir * 25) << 8);
    #pragma unroll
    for (int qi = 0; qi < 7; ++qi) {
      int q = w + qi * 4;
      if (q < 25) pvA[qi] = *reinterpret_cast<const uint2*>(pb + (q << 8) + s * 16 + lk * 4);
    }
  }
  __syncthreads();

  auto step = [&](uint2 (&pvc)[7], uint2 (&pvn)[7], int t) {
    f32x4 acc[7];
    #pragma unroll
    for (int qi = 0; qi < 7; ++qi)
      #pragma unroll
      for (int r = 0; r < 4; ++r) acc[qi][r] = 0.f;
    #pragma unroll
    for (int ks = 0; ks < 4; ++ks) {
      short8 af = *reinterpret_cast<const short8*>(
          &h_lds[s * 128 + (((ks * 4 + lk) ^ s) << 3)]);
      #pragma unroll
      for (int qi = 0; qi < 7; ++qi)
        if (w + qi * 4 < 25)
          acc[qi] = __builtin_amdgcn_mfma_f32_16x16x32_bf16(af, wf[qi][ks], acc[qi], 0, 0, 0);
    }
    #pragma unroll
    for (int qi = 0; qi < 7; ++qi)
      if (w + qi * 4 < 25) {
        acc[qi][0] += bflo(pvc[qi].x); acc[qi][1] += bfhi(pvc[qi].x);
        acc[qi][2] += bflo(pvc[qi].y); acc[qi][3] += bfhi(pvc[qi].y);
      }
    if (t + 1 < 20) {
      int tn = dir ? 19 - (t + 1) : (t + 1);
      const ushort_t* pb = pre + ((((size_t)tn * 250 + c) * 50 + dir * 25) << 8);
      #pragma unroll
      for (int qi = 0; qi < 7; ++qi) {
        int q = w + qi * 4;
        if (q < 25) pvn[qi] = *reinterpret_cast<const uint2*>(pb + (q << 8) + s * 16 + lk * 4);
      }
    }
    #pragma unroll
    for (int qi = 0; qi < 7; ++qi) {
      int q = w + qi * 4;
      if (q < 25) {
        ushort4 pk;
        pk.x = f2bf(acc[qi][0]); pk.y = f2bf(acc[qi][1]);
        pk.z = f2bf(acc[qi][2]); pk.w = f2bf(acc[qi][3]);
        *reinterpret_cast<ushort4*>(&gx[(q << 8) + s * 16 + lk * 4]) = pk;
      }
    }
    __syncthreads();
    #pragma unroll
    for (int gd = 0; gd < 2; ++gd) {
      int gi = w + gd * 4;
      if (gi < 7) {
        int j = gi * 16 + s;
        if (j < 100) {
          auto ld2 = [&](int q, int sp) {
            return *reinterpret_cast<const uint2*>(&gx[(q << 8) + sp * 16 + lk * 4]);
          };
          uint2 iv = ld2(gi, s);
          uint2 fv = (s < 12) ? ld2(6 + gi, s + 4) : ld2(7 + gi, s - 12);
          uint2 gv = (s < 8) ? ld2(12 + gi, s + 8) : ld2(13 + gi, s - 8);
          uint2 ov = (s < 4) ? ld2(18 + gi, s + 12) : ld2(19 + gi, s - 4);
          float ia[4] = {bflo(iv.x), bfhi(iv.x), bflo(iv.y), bfhi(iv.y)};
          float fa[4] = {bflo(fv.x), bfhi(fv.x), bflo(fv.y), bfhi(fv.y)};
          float ga[4] = {bflo(gv.x), bfhi(gv.x), bflo(gv.y), bfhi(gv.y)};
          float oa[4] = {bflo(ov.x), bfhi(ov.x), bflo(ov.y), bfhi(ov.y)};
          #pragma unroll
          for (int r = 0; r < 4; ++r) {
            float cc = sigm(fa[r]) * cst[gd][r] + sigm(ia[r]) * tanh_f(ga[r]);
            cst[gd][r] = cc;
            int row = lk * 4 + r;
            h_lds[row * 128 + (((j >> 3) ^ row) << 3) + (j & 7)] =
                f2bf(sigm(oa[r]) * tanh_f(cc));
          }
        }
      }
    }
    __syncthreads();
  };

  #pragma unroll 1
  for (int tp = 0; tp < 10; ++tp) {
    step(pvA, pvB, 2 * tp);
    step(pvB, pvA, 2 * tp + 1);
  }

  {
    int row = tid >> 4, sl = tid & 15;
    uint2 v = *reinterpret_cast<const uint2*>(&h_lds[row * 128 + ((sl ^ row) << 3)]);
    *reinterpret_cast<uint2*>(&hcat[(size_t)(c * 16 + row) * 256 + dir * 128 + sl * 8]) = v;
  }
}

// ---------------- small kernels ----------------

__global__ void rowdot_cs(const float* __restrict__ cs,
                          const float* __restrict__ W2w, const float* __restrict__ W2b,
                          float* __restrict__ part2) {
  int row = blockIdx.x * 4 + (threadIdx.x >> 6);
  int lane = threadIdx.x & 63;
  const float* x = cs + (size_t)row * 768;
  float s = 0.f;
  for (int k = lane; k < 768; k += 64) s += x[k] * W2w[k];
  for (int off = 32; off; off >>= 1) s += __shfl_down(s, off);
  if (lane == 0) part2[row] = s + W2b[0];
}

__global__ void softmax_both(const float* __restrict__ t4,   // [4][40][128][100]
                             const float* __restrict__ part1,
                             const float* __restrict__ part2,
                             const int* __restrict__ amask,
                             const int* __restrict__ cmask,
                             ushort_t* __restrict__ csatt,
                             ushort_t* __restrict__ csTcat) {
  int bid = blockIdx.x;
  int lane = threadIdx.x;
  auto tsum = [&](size_t idx) {
    return t4[idx] + t4[idx + 512000] + t4[idx + 1024000] + t4[idx + 1536000];
  };
  if (bid < 5120) {
    int b = bid >> 7;
    size_t base = (size_t)bid * 100;
    float e0 = tsum(base + lane) + part2[b * 100 + lane]
               + (1.f - (float)cmask[b * 100 + lane]) * -10000.f;
    bool has1 = (lane + 64) < 100;
    float e1 = -3.4e38f;
    if (has1)
      e1 = tsum(base + lane + 64) + part2[b * 100 + lane + 64]
           + (1.f - (float)cmask[b * 100 + lane + 64]) * -10000.f;
    float m = fmaxf(e0, e1);
    for (int off = 32; off; off >>= 1) m = fmaxf(m, __shfl_xor(m, off));
    float s0 = expf(e0 - m), s1 = has1 ? expf(e1 - m) : 0.f;
    float s = s0 + s1;
    for (int off = 32; off; off >>= 1) s += __shfl_xor(s, off);
    float inv = 1.f / s;
    csatt[(size_t)bid * 128 + lane] = f2bf(s0 * inv);
    csatt[(size_t)bid * 128 + lane + 64] = has1 ? f2bf(s1 * inv) : (ushort_t)0;
  } else {
    int idx = bid - 5120;
    int b = idx / 100, p = idx - b * 100;
    size_t base = (size_t)b * 12800 + p;
    int t0 = lane, t1 = lane + 64;
    float e0 = tsum(base + (size_t)t0 * 100) + part1[b * 128 + t0]
               + (1.f - (float)amask[b * 128 + t0]) * -10000.f;
    float e1 = tsum(base + (size_t)t1 * 100) + part1[b * 128 + t1]
               + (1.f - (float)amask[b * 128 + t1]) * -10000.f;
    float m = fmaxf(e0, e1);
    for (int off = 32; off; off >>= 1) m = fmaxf(m, __shfl_xor(m, off));
    float s0 = expf(e0 - m), s1 = expf(e1 - m);
    float s = s0 + s1;
    for (int off = 32; off; off >>= 1) s += __shfl_xor(s, off);
    float inv = 1.f / s;
    csTcat[((size_t)b * 896 + 768 + t0) * 128 + p] = f2bf(s0 * inv);
    csTcat[((size_t)b * 896 + 768 + t1) * 128 + p] = f2bf(s1 * inv);
  }
}

__global__ __launch_bounds__(256) void layernorm(float* __restrict__ X,
                                                 const float* __restrict__ w,
                                                 const float* __restrict__ bta) {
  int row = blockIdx.x;
  float* x = X + (size_t)row * 768;
  int t = threadIdx.x;
  float v[3];
  float s = 0.f;
  #pragma unroll
  for (int i = 0; i < 3; ++i) { v[i] = x[t + 256 * i]; s += v[i]; }
  __shared__ float red[256];
  red[t] = s; __syncthreads();
  for (int off = 128; off; off >>= 1) { if (t < off) red[t] += red[t + off]; __syncthreads(); }
  float mean = red[0] * (1.f / 768.f);
  __syncthreads();
  float q = 0.f;
  #pragma unroll
  for (int i = 0; i < 3; ++i) { float d = v[i] - mean; q += d * d; }
  red[t] = q; __syncthreads();
  for (int off = 128; off; off >>= 1) { if (t < off) red[t] += red[t + off]; __syncthreads(); }
  float inv = rsqrtf(red[0] * (1.f / 768.f) + 1e-12f);
  #pragma unroll
  for (int i = 0; i < 3; ++i) {
    int k = t + 256 * i;
    x[k] = w[k] * ((v[i] - mean) * inv) + bta[k];
  }
}

// ---------------- host orchestration ----------------

extern "C" void kernel_launch(void* const* d_in, const int* in_sizes, int n_in,
                              void* d_out, int out_size, void* d_ws, size_t ws_size,
                              hipStream_t stream) {
  (void)in_sizes; (void)n_in; (void)out_size; (void)ws_size;
  const float* bert  = (const float*)d_in[0];
  const float* cmn   = (const float*)d_in[1];
  const int*   amask = (const int*)d_in[2];
  const int*   cmask = (const int*)d_in[3];
  const float* Wih_f = (const float*)d_in[8];
  const float* Whh_f = (const float*)d_in[9];
  const float* bih_f = (const float*)d_in[10];
  const float* bhh_f = (const float*)d_in[11];
  const float* Wih_b = (const float*)d_in[12];
  const float* Whh_b = (const float*)d_in[13];
  const float* bih_b = (const float*)d_in[14];
  const float* bhh_b = (const float*)d_in[15];
  const float* projW = (const float*)d_in[16];
  const float* projb = (const float*)d_in[17];
  const float* W1w   = (const float*)d_in[18];
  const float* W1b   = (const float*)d_in[19];
  const float* W2w   = (const float*)d_in[20];
  const float* W2b   = (const float*)d_in[21];
  const float* W3    = (const float*)d_in[22];
  const float* attpW = (const float*)d_in[23];
  const float* attpb = (const float*)d_in[24];
  const float* lnw   = (const float*)d_in[25];
  const float* lnb   = (const float*)d_in[26];

  char* base = (char*)d_ws;
  size_t off = 0;
  auto alloc = [&](size_t bytes) -> char* {
    char* r = base + off;
    off += (bytes + 255) & ~(size_t)255;
    return r;
  };
  ushort_t* wihcat   = (ushort_t*)alloc(800 * 768 * 2);
  ushort_t* whhcat   = (ushort_t*)alloc(800 * 128 * 2);
  float*    biascat  = (float*)alloc(800 * 4);
  ushort_t* projw_bf = (ushort_t*)alloc(768 * 256 * 2);
  ushort_t* attpw_bf = (ushort_t*)alloc(768 * 3072 * 2);
  ushort_t* hcat     = (ushort_t*)alloc(4000 * 256 * 2);
  float*    cs       = (float*)alloc((size_t)4000 * 768 * 4);
  ushort_t* cs_bf    = (ushort_t*)alloc((size_t)4000 * 768 * 2);
  ushort_t* csTcat   = (ushort_t*)alloc((size_t)40 * 896 * 128 * 2);
  float*    part1    = (float*)alloc(5120 * 4);
  float*    part2    = (float*)alloc(4000 * 4);
  float*    total4   = (float*)alloc((size_t)4 * 40 * 128 * 100 * 4);
  ushort_t* csatt_bf = (ushort_t*)alloc((size_t)40 * 128 * 128 * 2);
  ushort_t* probs_bf = (ushort_t*)alloc((size_t)40 * 128 * 128 * 2);
  ushort_t* bw3_bf   = (ushort_t*)alloc((size_t)40 * 128 * 768 * 2);
  ushort_t* bertT    = (ushort_t*)alloc((size_t)40 * 768 * 128 * 2);
  ushort_t* cat      = (ushort_t*)alloc((size_t)5120 * 3072 * 2);
  ushort_t* x_bf     = (ushort_t*)alloc((size_t)20 * 4000 * 768 * 2);
  ushort_t* pre      = (ushort_t*)alloc((size_t)20 * 250 * 50 * 256 * 2);

  // fused prep: weights | bert (bw3/bT/cat seg0) | x convert | part1
  prep_all<<<4320, 256, 0, stream>>>(
      Wih_f, Wih_b, Whh_f, Whh_b, bih_f, bhh_f, bih_b, bhh_b, projW, attpW,
      wihcat, whhcat, biascat, projw_bf, attpw_bf,
      bert, W3, bw3_bf, bertT, cat,
      (const float4*)cmn, x_bf,
      W1w, W1b, part1);

  // pre = x @ Wih^T + (bih+bhh): 128x160 tiles, counted-vmcnt dbuf, XCD-chunked
  gemm_pre160<<<3125, 256, 0, stream>>>(x_bf, wihcat, biascat, pre);
  lstm_recur<<<dim3(250, 2), 256, 0, stream>>>(pre, whhcat, hcat);

  // cs = relu(hcat @ projW^T + projb): f32 + bf16 + csT (transposed)
  gemm_proj<<<dim3(32, 6), 256, 0, stream>>>(hcat, 256, projw_bf, 256, 4000, 768, 4,
                                             projb, cs, 768, cs_bf, csTcat);
  rowdot_cs<<<1000, 256, 0, stream>>>(cs, W2w, W2b, part2);

  // total partials: (W3*bert) @ cs^T, splitK=4
  gemm128b<10><<<dim3(1, 4, 40), 256, 0, stream>>>(
      bw3_bf, 98304LL, 768, cs_bf, 76800LL, 768, 128, 100, 3,
      total4, nullptr, nullptr, nullptr);
  softmax_both<<<9120, 64, 0, stream>>>(total4, part1, part2, amask, cmask,
                                        csatt_bf, csTcat);
  // merged: [wcs -> cat seg1+seg2 | probs] = cs_att @ [csT; ctx_att]
  gemm128b<12><<<dim3(7, 1, 40), 256, 0, stream>>>(
      csatt_bf, 16384LL, 128, csTcat, 114688LL, 128, 128, 896, 2,
      nullptr, probs_bf, bert, cat);
  // wctx -> cat seg3 = bf16(bert * probs@bertT)
  gemm128b<13><<<dim3(6, 1, 40), 256, 0, stream>>>(
      probs_bf, 16384LL, 128, bertT, 98304LL, 128, 128, 768, 2,
      nullptr, nullptr, bert, cat);

  // x = relu(cat @ attpW^T + attpb) + bert -> d_out, then LN in place
  gemm64_attp<<<480, 256, 0, stream>>>(cat, attpw_bf, attpb, bert, (float*)d_out);
  layernorm<<<5120, 256, 0, stream>>>((float*)d_out, lnw, lnb);
}